// Round 8
// baseline (11202.065 us; speedup 1.0000x reference)
//
#include <hip/hip_runtime.h>
#include <math.h>

#define B_ROWS 8192
#define P_KEYS 2048
#define D_DIM  768
#define L_LEN  5
#define K_SEL  5
#define EPSV   1e-8f

#define ROW_TILE 128
#define COL_TILE 128
#define KB 16
#define NCB (P_KEYS / COL_TILE)   // 16 column blocks

// sorted ascending (v[0] best). Tie-break: lower index wins (jax top_k semantics).
__device__ inline void insert5(float (&v)[K_SEL], int (&ix)[K_SEL], float nv, int ni) {
    if (nv < v[K_SEL-1] || (nv == v[K_SEL-1] && ni < ix[K_SEL-1])) {
        v[K_SEL-1] = nv; ix[K_SEL-1] = ni;
        #pragma unroll
        for (int j = K_SEL-1; j > 0; --j) {
            bool sw = (v[j] < v[j-1]) || (v[j] == v[j-1] && ix[j] < ix[j-1]);
            if (sw) {
                float tv = v[j]; v[j] = v[j-1]; v[j-1] = tv;
                int   ti = ix[j]; ix[j] = ix[j-1]; ix[j-1] = ti;
            }
        }
    }
}

// One wave per row: inverse norms only. waves [0,B_ROWS): x -> inv_x.
// waves [B_ROWS, B_ROWS+P_KEYS): pool_key -> inv_k.
__global__ __launch_bounds__(256)
void norm_kernel(const float* __restrict__ x, const float* __restrict__ pk,
                 float* __restrict__ inv_x, float* __restrict__ inv_k) {
    int wave = (blockIdx.x * blockDim.x + threadIdx.x) >> 6;
    int lane = threadIdx.x & 63;
    bool is_x = (wave < B_ROWS);
    int row = is_x ? wave : wave - B_ROWS;
    const float* src = is_x ? (x + (size_t)row * D_DIM) : (pk + (size_t)row * D_DIM);

    const float4* s4 = (const float4*)src;
    float s = 0.f;
    #pragma unroll
    for (int i = 0; i < 3; ++i) {
        float4 v = s4[lane + 64 * i];
        s += v.x * v.x + v.y * v.y + v.z * v.z + v.w * v.w;
    }
    #pragma unroll
    for (int off = 32; off; off >>= 1) s += __shfl_xor(s, off, 64);
    float inv = 1.0f / fmaxf(sqrtf(s), EPSV);
    if (lane == 0) {
        if (is_x) inv_x[row] = inv; else inv_k[row] = inv;
    }
}

// Fused fp32 GEMM (dist = 1 - x_hat . k_hat) + per-row top-5 per 128-col block.
// grid = (NCB, B_ROWS/ROW_TILE). block 256 = 16x16, each thread 8x8 outputs
// arranged as 2x2 blocks of 4x4 (rows ty*4+{0..3}/+64, cols tx*4+{0..3}/+64).
//
// waves_per_eu PINNED (3,3): __launch_bounds__(256,N) sets only the MIN of
// amdgpu-waves-per-eu; the allocator still TARGETED 7-8 waves/EU (observed
// VGPR 64=512/8, then 72~512/7) and spilled acc[8][8] to scratch (24-27 GB
// scratch traffic, VALUBusy 2.9%). Closing the range to (3,3) gives a
// 512/3=168-VGPR budget — room for the ~130 this kernel needs — and 3
// blocks/CU.
__global__ __attribute__((amdgpu_waves_per_eu(3, 3))) __launch_bounds__(256)
void gemm_top5_kernel(const float* __restrict__ x, const float* __restrict__ pk,
                      const float* __restrict__ inv_x, const float* __restrict__ inv_k,
                      float* __restrict__ cand_val, int* __restrict__ cand_idx) {
    const int cb   = blockIdx.x;
    const int rb   = blockIdx.y;
    const int row0 = rb * ROW_TILE;
    const int col0 = cb * COL_TILE;

    __shared__ float As[KB][ROW_TILE + 4];   // k-major; stride 132 floats
    __shared__ float Bs[KB][COL_TILE + 4];

    const int tid = threadIdx.x;
    const int tx = tid & 15, ty = tid >> 4;

    // staging: thread loads rows sr & sr+64, k-cols sk..sk+3 of both panels
    const int sr = tid >> 2;          // 0..63
    const int sk = (tid & 3) * 4;     // 0,4,8,12
    const float iva0 = inv_x[row0 + sr];
    const float iva1 = inv_x[row0 + sr + 64];
    const float ivb0 = inv_k[col0 + sr];
    const float ivb1 = inv_k[col0 + sr + 64];
    const float* ap0 = x  + (size_t)(row0 + sr)      * D_DIM + sk;
    const float* ap1 = x  + (size_t)(row0 + sr + 64) * D_DIM + sk;
    const float* bp0 = pk + (size_t)(col0 + sr)      * D_DIM + sk;
    const float* bp1 = pk + (size_t)(col0 + sr + 64) * D_DIM + sk;

    float acc[8][8] = {};

    for (int k0 = 0; k0 < D_DIM; k0 += KB) {
        float4 a0 = *(const float4*)(ap0 + k0);
        float4 a1 = *(const float4*)(ap1 + k0);
        float4 b0 = *(const float4*)(bp0 + k0);
        float4 b1 = *(const float4*)(bp1 + k0);
        __syncthreads();
        As[sk+0][sr]    = a0.x * iva0; As[sk+1][sr]    = a0.y * iva0;
        As[sk+2][sr]    = a0.z * iva0; As[sk+3][sr]    = a0.w * iva0;
        As[sk+0][sr+64] = a1.x * iva1; As[sk+1][sr+64] = a1.y * iva1;
        As[sk+2][sr+64] = a1.z * iva1; As[sk+3][sr+64] = a1.w * iva1;
        Bs[sk+0][sr]    = b0.x * ivb0; Bs[sk+1][sr]    = b0.y * ivb0;
        Bs[sk+2][sr]    = b0.z * ivb0; Bs[sk+3][sr]    = b0.w * ivb0;
        Bs[sk+0][sr+64] = b1.x * ivb1; Bs[sk+1][sr+64] = b1.y * ivb1;
        Bs[sk+2][sr+64] = b1.z * ivb1; Bs[sk+3][sr+64] = b1.w * ivb1;
        __syncthreads();

        #pragma unroll
        for (int k = 0; k < KB; ++k) {
            float4 al = *(const float4*)&As[k][ty * 4];
            float4 ah = *(const float4*)&As[k][ty * 4 + 64];
            float4 bl = *(const float4*)&Bs[k][tx * 4];
            float4 bh = *(const float4*)&Bs[k][tx * 4 + 64];
            float ar[8] = {al.x, al.y, al.z, al.w, ah.x, ah.y, ah.z, ah.w};
            float br[8] = {bl.x, bl.y, bl.z, bl.w, bh.x, bh.y, bh.z, bh.w};
            #pragma unroll
            for (int i = 0; i < 8; ++i)
                #pragma unroll
                for (int j = 0; j < 8; ++j)
                    acc[i][j] += ar[i] * br[j];
        }
    }

    // epilogue: per row-slot local top5 over 8 cols, then 16-lane butterfly merge
    #pragma unroll
    for (int i = 0; i < 8; ++i) {
        float tv[K_SEL]; int tix[K_SEL];
        #pragma unroll
        for (int j = 0; j < K_SEL; ++j) { tv[j] = 3.0e38f; tix[j] = 0x7fffffff; }
        #pragma unroll
        for (int j = 0; j < 8; ++j) {
            float dv = 1.0f - acc[i][j];
            int c = col0 + tx * 4 + (j >> 2) * 64 + (j & 3);
            insert5(tv, tix, dv, c);
        }
        #pragma unroll
        for (int off = 1; off < 16; off <<= 1) {
            float ov[K_SEL]; int oi[K_SEL];
            #pragma unroll
            for (int j = 0; j < K_SEL; ++j) {
                ov[j] = __shfl_xor(tv[j], off, 16);
                oi[j] = __shfl_xor(tix[j], off, 16);
            }
            #pragma unroll
            for (int j = 0; j < K_SEL; ++j) insert5(tv, tix, ov[j], oi[j]);
        }
        if (tx == 0) {
            int grow = row0 + ty * 4 + (i >> 2) * 64 + (i & 3);
            #pragma unroll
            for (int j = 0; j < K_SEL; ++j) {
                cand_val[((size_t)grow * NCB + cb) * K_SEL + j] = tv[j];
                cand_idx[((size_t)grow * NCB + cb) * K_SEL + j] = tix[j];
            }
        }
    }
}

__global__ __launch_bounds__(256)
void merge_kernel(const float* __restrict__ cand_val, const int* __restrict__ cand_idx,
                  float* __restrict__ out_dist, int* __restrict__ final_idx) {
    int row = blockIdx.x * blockDim.x + threadIdx.x;
    if (row >= B_ROWS) return;
    float fv[K_SEL]; int fi[K_SEL];
    #pragma unroll
    for (int j = 0; j < K_SEL; ++j) { fv[j] = 3.0e38f; fi[j] = 0x7fffffff; }
    for (int t = 0; t < NCB * K_SEL; ++t)
        insert5(fv, fi, cand_val[(size_t)row * NCB * K_SEL + t],
                        cand_idx[(size_t)row * NCB * K_SEL + t]);
    #pragma unroll
    for (int j = 0; j < K_SEL; ++j) {
        out_dist[(size_t)row * K_SEL + j] = fv[j];
        final_idx[(size_t)row * K_SEL + j] = fi[j];
    }
}

// one block per (b, s): copy prompts[idx] (5*768 floats = 960 float4) to output
__global__ __launch_bounds__(256)
void gather_kernel(const float* __restrict__ prompts, const int* __restrict__ final_idx,
                   float* __restrict__ out1) {
    int bs = blockIdx.x;                 // 0 .. B_ROWS*K_SEL-1
    int p = final_idx[bs];
    const float4* src = (const float4*)(prompts + (size_t)p * (L_LEN * D_DIM));
    float4* dst = (float4*)(out1 + (size_t)bs * (L_LEN * D_DIM));
    const int n4 = (L_LEN * D_DIM) / 4;  // 960
    for (int i = threadIdx.x; i < n4; i += blockDim.x) dst[i] = src[i];
}

extern "C" void kernel_launch(void* const* d_in, const int* in_sizes, int n_in,
                              void* d_out, int out_size, void* d_ws, size_t ws_size,
                              hipStream_t stream) {
    const float* x       = (const float*)d_in[0];   // [8192, 768]
    const float* pk      = (const float*)d_in[1];   // [2048, 768]
    const float* prompts = (const float*)d_in[2];   // [2048, 5, 768]

    float* out_dist = (float*)d_out;                          // [8192, 5]
    float* out_pr   = (float*)d_out + (size_t)B_ROWS * K_SEL; // [8192, 5, 5, 768]

    char* ws = (char*)d_ws;
    float* inv_x    = (float*)(ws);                    //    32,768 B
    float* inv_k    = (float*)(ws + 32768);            //     8,192 B
    float* cand_val = (float*)(ws + 40960);            // 2,621,440 B
    int*   cand_idx = (int*)  (ws + 40960 + 2621440);  // 2,621,440 B
    int*   final_ix = (int*)  (ws + 40960 + 5242880);  //   163,840 B

    // 1) inverse norms: (B_ROWS + P_KEYS) waves, 4 waves/block
    norm_kernel<<<(B_ROWS + P_KEYS) / 4, 256, 0, stream>>>(x, pk, inv_x, inv_k);
    // 2) fused GEMM + per-colblock top5
    {
        dim3 grid(NCB, B_ROWS / ROW_TILE);
        gemm_top5_kernel<<<grid, 256, 0, stream>>>(x, pk, inv_x, inv_k, cand_val, cand_idx);
    }
    // 3) cross-colblock merge
    merge_kernel<<<B_ROWS / 256, 256, 0, stream>>>(cand_val, cand_idx, out_dist, final_ix);
    // 4) gather prompts
    gather_kernel<<<B_ROWS * K_SEL, 256, 0, stream>>>(prompts, final_ix, out_pr);
}

// Round 9
// 902.827 us; speedup vs baseline: 12.4078x; 12.4078x over previous
//
#include <hip/hip_runtime.h>
#include <math.h>

#define B_ROWS 8192
#define P_KEYS 2048
#define D_DIM  768
#define L_LEN  5
#define K_SEL  5
#define EPSV   1e-8f

#define ROW_TILE 128
#define COL_TILE 128
#define KB 16
#define NCB (P_KEYS / COL_TILE)   // 16 column blocks

// sorted ascending (v[0] best). Tie-break: lower index wins (jax top_k semantics).
__device__ inline void insert5(float (&v)[K_SEL], int (&ix)[K_SEL], float nv, int ni) {
    if (nv < v[K_SEL-1] || (nv == v[K_SEL-1] && ni < ix[K_SEL-1])) {
        v[K_SEL-1] = nv; ix[K_SEL-1] = ni;
        #pragma unroll
        for (int j = K_SEL-1; j > 0; --j) {
            bool sw = (v[j] < v[j-1]) || (v[j] == v[j-1] && ix[j] < ix[j-1]);
            if (sw) {
                float tv = v[j]; v[j] = v[j-1]; v[j-1] = tv;
                int   ti = ix[j]; ix[j] = ix[j-1]; ix[j-1] = ti;
            }
        }
    }
}

// One wave per row: inverse norms only. waves [0,B_ROWS): x -> inv_x.
// waves [B_ROWS, B_ROWS+P_KEYS): pool_key -> inv_k.
__global__ __launch_bounds__(256)
void norm_kernel(const float* __restrict__ x, const float* __restrict__ pk,
                 float* __restrict__ inv_x, float* __restrict__ inv_k) {
    int wave = (blockIdx.x * blockDim.x + threadIdx.x) >> 6;
    int lane = threadIdx.x & 63;
    bool is_x = (wave < B_ROWS);
    int row = is_x ? wave : wave - B_ROWS;
    const float* src = is_x ? (x + (size_t)row * D_DIM) : (pk + (size_t)row * D_DIM);

    const float4* s4 = (const float4*)src;
    float s = 0.f;
    #pragma unroll
    for (int i = 0; i < 3; ++i) {
        float4 v = s4[lane + 64 * i];
        s += v.x * v.x + v.y * v.y + v.z * v.z + v.w * v.w;
    }
    #pragma unroll
    for (int off = 32; off; off >>= 1) s += __shfl_xor(s, off, 64);
    float inv = 1.0f / fmaxf(sqrtf(s), EPSV);
    if (lane == 0) {
        if (is_x) inv_x[row] = inv; else inv_k[row] = inv;
    }
}

// Fused fp32 GEMM (dist = 1 - x_hat . k_hat) + per-row top-5 per 128-col block.
// grid = (NCB, B_ROWS/ROW_TILE), block 512 (8 waves).
// Each thread: 4 rows (ty*4+i, ty=0..31) x 8 cols (tx*4+{0..3}, +64) -> 32 acc.
//
// REGISTER-PRESSURE NOTE (r3-r8 history): the 8x8-microtile/256-thread variant
// spilled its 64-float acc to scratch (24-31 GB scratch traffic, VALUBusy 2.9%)
// under EVERY occupancy hint tried (launch_bounds(256,4)->64 VGPR,
// (256,2)->72, waves_per_eu(3,3)->84) — the backend's occupancy-first
// heuristic refuses to hold ~110 live VGPRs in a loop with 8 hoistable
// ds_read_b128 per k-step. Fix is structural: 32-float acc + 12 frag floats
// fits the allocator's preferred <=64-VGPR/8-wave budget, so there is
// nothing to spill. Round-2 empirics (4x4 acc, 88 VGPR, no spill) support.
__global__ __launch_bounds__(512)
void gemm_top5_kernel(const float* __restrict__ x, const float* __restrict__ pk,
                      const float* __restrict__ inv_x, const float* __restrict__ inv_k,
                      float* __restrict__ cand_val, int* __restrict__ cand_idx) {
    const int cb   = blockIdx.x;
    const int rb   = blockIdx.y;
    const int row0 = rb * ROW_TILE;
    const int col0 = cb * COL_TILE;

    __shared__ float As[KB][ROW_TILE + 4];   // k-major; stride 132 floats
    __shared__ float Bs[KB][COL_TILE + 4];

    const int tid = threadIdx.x;
    const int tx = tid & 15;          // 0..15 -> col group
    const int ty = tid >> 4;          // 0..31 -> row group

    // staging: each thread loads ONE float4 of A and ONE of B per k0-step
    const int sr = tid >> 2;          // 0..127 (tile row)
    const int sk = (tid & 3) * 4;     // 0,4,8,12 (k quad)
    const float iva = inv_x[row0 + sr];
    const float ivb = inv_k[col0 + sr];
    const float* ap = x  + (size_t)(row0 + sr) * D_DIM + sk;
    const float* bp = pk + (size_t)(col0 + sr) * D_DIM + sk;

    float acc[4][8] = {};

    for (int k0 = 0; k0 < D_DIM; k0 += KB) {
        float4 av = *(const float4*)(ap + k0);
        float4 bv = *(const float4*)(bp + k0);
        __syncthreads();
        As[sk+0][sr] = av.x * iva; As[sk+1][sr] = av.y * iva;
        As[sk+2][sr] = av.z * iva; As[sk+3][sr] = av.w * iva;
        Bs[sk+0][sr] = bv.x * ivb; Bs[sk+1][sr] = bv.y * ivb;
        Bs[sk+2][sr] = bv.z * ivb; Bs[sk+3][sr] = bv.w * ivb;
        __syncthreads();

        #pragma unroll
        for (int k = 0; k < KB; ++k) {
            float4 a4 = *(const float4*)&As[k][ty * 4];
            float4 bl = *(const float4*)&Bs[k][tx * 4];
            float4 bh = *(const float4*)&Bs[k][tx * 4 + 64];
            float ar[4] = {a4.x, a4.y, a4.z, a4.w};
            float br[8] = {bl.x, bl.y, bl.z, bl.w, bh.x, bh.y, bh.z, bh.w};
            #pragma unroll
            for (int i = 0; i < 4; ++i)
                #pragma unroll
                for (int j = 0; j < 8; ++j)
                    acc[i][j] += ar[i] * br[j];
        }
    }

    // epilogue: per row local top5 over 8 cols, then 16-lane butterfly merge
    #pragma unroll
    for (int i = 0; i < 4; ++i) {
        float tv[K_SEL]; int tix[K_SEL];
        #pragma unroll
        for (int j = 0; j < K_SEL; ++j) { tv[j] = 3.0e38f; tix[j] = 0x7fffffff; }
        #pragma unroll
        for (int j = 0; j < 8; ++j) {
            float dv = 1.0f - acc[i][j];
            int c = col0 + tx * 4 + (j >> 2) * 64 + (j & 3);
            insert5(tv, tix, dv, c);
        }
        #pragma unroll
        for (int off = 1; off < 16; off <<= 1) {
            float ov[K_SEL]; int oi[K_SEL];
            #pragma unroll
            for (int j = 0; j < K_SEL; ++j) {
                ov[j] = __shfl_xor(tv[j], off, 16);
                oi[j] = __shfl_xor(tix[j], off, 16);
            }
            #pragma unroll
            for (int j = 0; j < K_SEL; ++j) insert5(tv, tix, ov[j], oi[j]);
        }
        if (tx == 0) {
            int grow = row0 + ty * 4 + i;
            #pragma unroll
            for (int j = 0; j < K_SEL; ++j) {
                cand_val[((size_t)grow * NCB + cb) * K_SEL + j] = tv[j];
                cand_idx[((size_t)grow * NCB + cb) * K_SEL + j] = tix[j];
            }
        }
    }
}

__global__ __launch_bounds__(256)
void merge_kernel(const float* __restrict__ cand_val, const int* __restrict__ cand_idx,
                  float* __restrict__ out_dist, int* __restrict__ final_idx) {
    int row = blockIdx.x * blockDim.x + threadIdx.x;
    if (row >= B_ROWS) return;
    float fv[K_SEL]; int fi[K_SEL];
    #pragma unroll
    for (int j = 0; j < K_SEL; ++j) { fv[j] = 3.0e38f; fi[j] = 0x7fffffff; }
    for (int t = 0; t < NCB * K_SEL; ++t)
        insert5(fv, fi, cand_val[(size_t)row * NCB * K_SEL + t],
                        cand_idx[(size_t)row * NCB * K_SEL + t]);
    #pragma unroll
    for (int j = 0; j < K_SEL; ++j) {
        out_dist[(size_t)row * K_SEL + j] = fv[j];
        final_idx[(size_t)row * K_SEL + j] = fi[j];
    }
}

// one block per (b, s): copy prompts[idx] (5*768 floats = 960 float4) to output
__global__ __launch_bounds__(256)
void gather_kernel(const float* __restrict__ prompts, const int* __restrict__ final_idx,
                   float* __restrict__ out1) {
    int bs = blockIdx.x;                 // 0 .. B_ROWS*K_SEL-1
    int p = final_idx[bs];
    const float4* src = (const float4*)(prompts + (size_t)p * (L_LEN * D_DIM));
    float4* dst = (float4*)(out1 + (size_t)bs * (L_LEN * D_DIM));
    const int n4 = (L_LEN * D_DIM) / 4;  // 960
    for (int i = threadIdx.x; i < n4; i += blockDim.x) dst[i] = src[i];
}

extern "C" void kernel_launch(void* const* d_in, const int* in_sizes, int n_in,
                              void* d_out, int out_size, void* d_ws, size_t ws_size,
                              hipStream_t stream) {
    const float* x       = (const float*)d_in[0];   // [8192, 768]
    const float* pk      = (const float*)d_in[1];   // [2048, 768]
    const float* prompts = (const float*)d_in[2];   // [2048, 5, 768]

    float* out_dist = (float*)d_out;                          // [8192, 5]
    float* out_pr   = (float*)d_out + (size_t)B_ROWS * K_SEL; // [8192, 5, 5, 768]

    char* ws = (char*)d_ws;
    float* inv_x    = (float*)(ws);                    //    32,768 B
    float* inv_k    = (float*)(ws + 32768);            //     8,192 B
    float* cand_val = (float*)(ws + 40960);            // 2,621,440 B
    int*   cand_idx = (int*)  (ws + 40960 + 2621440);  // 2,621,440 B
    int*   final_ix = (int*)  (ws + 40960 + 5242880);  //   163,840 B

    // 1) inverse norms: (B_ROWS + P_KEYS) waves, 4 waves/block
    norm_kernel<<<(B_ROWS + P_KEYS) / 4, 256, 0, stream>>>(x, pk, inv_x, inv_k);
    // 2) fused GEMM + per-colblock top5
    {
        dim3 grid(NCB, B_ROWS / ROW_TILE);
        gemm_top5_kernel<<<grid, 512, 0, stream>>>(x, pk, inv_x, inv_k, cand_val, cand_idx);
    }
    // 3) cross-colblock merge
    merge_kernel<<<B_ROWS / 256, 256, 0, stream>>>(cand_val, cand_idx, out_dist, final_ix);
    // 4) gather prompts
    gather_kernel<<<B_ROWS * K_SEL, 256, 0, stream>>>(prompts, final_ix, out_pr);
}

// Round 11
// 841.804 us; speedup vs baseline: 13.3072x; 1.0725x over previous
//
#include <hip/hip_runtime.h>
#include <math.h>

#define B_ROWS 8192
#define P_KEYS 2048
#define D_DIM  768
#define L_LEN  5
#define K_SEL  5
#define EPSV   1e-8f

#define RTILE 128
#define CTILE 128
#define KB 32
#define NCB (P_KEYS / CTILE)      // 16 column blocks
#define LDS_STRIDE 36             // floats per LDS row: 144B, 16B-aligned, banks spread

// sorted ascending (v[0] best). Tie-break: lower index wins (jax top_k semantics).
__device__ inline void insert5(float (&v)[K_SEL], int (&ix)[K_SEL], float nv, int ni) {
    if (nv < v[K_SEL-1] || (nv == v[K_SEL-1] && ni < ix[K_SEL-1])) {
        v[K_SEL-1] = nv; ix[K_SEL-1] = ni;
        #pragma unroll
        for (int j = K_SEL-1; j > 0; --j) {
            bool sw = (v[j] < v[j-1]) || (v[j] == v[j-1] && ix[j] < ix[j-1]);
            if (sw) {
                float tv = v[j]; v[j] = v[j-1]; v[j-1] = tv;
                int   ti = ix[j]; ix[j] = ix[j-1]; ix[j-1] = ti;
            }
        }
    }
}

// One wave (64 lanes) per row. waves [0, P_KEYS): normalize pool_key -> kn
// (pre-normalized B so GEMM numerics match the reference's x_hat . k_hat
// per-element rounding — r10's post-scale variant flipped a near-tied top-5
// index). waves [P_KEYS, ...): x -> inv_x only.
__global__ __launch_bounds__(256)
void norm_kernel(const float* __restrict__ x, const float* __restrict__ pk,
                 float* __restrict__ kn, float* __restrict__ inv_x) {
    int wave = (blockIdx.x * blockDim.x + threadIdx.x) >> 6;
    int lane = threadIdx.x & 63;
    bool is_key = (wave < P_KEYS);
    int row = is_key ? wave : wave - P_KEYS;
    const float* src = is_key ? (pk + (size_t)row * D_DIM) : (x + (size_t)row * D_DIM);

    const float4* s4 = (const float4*)src;
    float4 v[3];
    float s = 0.f;
    #pragma unroll
    for (int i = 0; i < 3; ++i) {
        v[i] = s4[lane + 64 * i];
        s += v[i].x * v[i].x + v[i].y * v[i].y + v[i].z * v[i].z + v[i].w * v[i].w;
    }
    #pragma unroll
    for (int off = 32; off; off >>= 1) s += __shfl_xor(s, off, 64);
    float inv = 1.0f / fmaxf(sqrtf(s), EPSV);

    if (is_key) {
        float4* d4 = (float4*)(kn + (size_t)row * D_DIM);
        #pragma unroll
        for (int i = 0; i < 3; ++i) {
            float4 w = v[i];
            w.x *= inv; w.y *= inv; w.z *= inv; w.w *= inv;
            d4[lane + 64 * i] = w;
        }
    } else {
        if (lane == 0) inv_x[row] = inv;
    }
}

// Fused fp32 GEMM (dist = 1 - x_hat . k_hat) + per-row top-5 per 128-col block.
// DS-pipe-bound fix (r9 post-mortem): B operands are WAVE-UNIFORM -> SGPRs via
// the scalar cache (s_load), costing zero DS/VMEM pipe; only A comes through
// LDS (4 ds_read_b128 per lane per 8-k chunk vs r9's 3 per single k). Each
// wave owns 8 cols; each lane owns rows {lane, lane+64} completely -> top-5
// epilogue needs no cross-lane butterfly. B is read from kn (pre-normalized)
// so the accumulation is bitwise-identical to the r9 kernel that passed.
// VGPR need ~55 — under the allocator's 64-VGPR/8-wave comfort zone, so the
// r3-r8 spill pathology cannot recur.
// grid = (NCB, B_ROWS/RTILE), block = 1024 (16 waves).
__global__ __launch_bounds__(1024)
void gemm_top5_kernel(const float* __restrict__ x, const float* __restrict__ kn,
                      const float* __restrict__ inv_x,
                      float* __restrict__ cand_val, int* __restrict__ cand_idx) {
    const int cb   = blockIdx.x;
    const int rb   = blockIdx.y;
    const int row0 = rb * RTILE;
    const int tid  = threadIdx.x;
    const int lane = tid & 63;
    const int w    = __builtin_amdgcn_readfirstlane(tid >> 6);  // wave id 0..15 (uniform)
    const int col0w = cb * CTILE + w * 8;                        // this wave's 8 cols

    // 40 KB LDS, time-shared: phase 1 = As[128][36] (18.4 KB), phase 2 = merge
    __shared__ float smem[10240];
    float* As   = smem;
    float* mval = smem;                    // [row][8 slots][5]  = 5120 floats
    int*   midx = (int*)smem + 128 * 8 * K_SEL;

    // A staging: 1024 threads x 1 float4 = 128 rows x 32 k
    const int sr  = tid >> 3;              // 0..127
    const int skq = (tid & 7) * 4;         // 0,4,...,28
    const float iva = inv_x[row0 + sr];
    const float* ap = x + (size_t)(row0 + sr) * D_DIM + skq;

    float acc[2][8] = {};

    float4 av = *(const float4*)ap;        // first slab
    for (int k0 = 0; k0 < D_DIM; k0 += KB) {
        __syncthreads();
        {
            float4 t = av;
            t.x *= iva; t.y *= iva; t.z *= iva; t.w *= iva;
            *(float4*)&As[sr * LDS_STRIDE + skq] = t;
        }
        __syncthreads();
        // prefetch next slab (latency hides under compute below)
        int knext = (k0 + KB < D_DIM) ? (k0 + KB) : 0;
        av = *(const float4*)(ap + knext);

        #pragma unroll
        for (int ch = 0; ch < 4; ++ch) {   // 8-k chunks
            float4 a00 = *(const float4*)&As[lane * LDS_STRIDE + ch * 8];
            float4 a01 = *(const float4*)&As[lane * LDS_STRIDE + ch * 8 + 4];
            float4 a10 = *(const float4*)&As[(lane + 64) * LDS_STRIDE + ch * 8];
            float4 a11 = *(const float4*)&As[(lane + 64) * LDS_STRIDE + ch * 8 + 4];
            float a0[8] = {a00.x, a00.y, a00.z, a00.w, a01.x, a01.y, a01.z, a01.w};
            float a1[8] = {a10.x, a10.y, a10.z, a10.w, a11.x, a11.y, a11.z, a11.w};
            #pragma unroll
            for (int c = 0; c < 8; ++c) {
                // wave-uniform address -> scalar loads (SGPR b-operand in v_fma)
                const float* bp = kn + (size_t)(col0w + c) * D_DIM + k0 + ch * 8;
                #pragma unroll
                for (int j = 0; j < 8; ++j) {
                    float b = bp[j];
                    acc[0][c] += a0[j] * b;
                    acc[1][c] += a1[j] * b;
                }
            }
        }
    }

    // epilogue: dist = 1 - acc; per-lane top5 over this wave's 8 cols
    float tv0[K_SEL], tv1[K_SEL]; int ti0[K_SEL], ti1[K_SEL];
    #pragma unroll
    for (int j = 0; j < K_SEL; ++j) {
        tv0[j] = 3.0e38f; ti0[j] = 0x7fffffff;
        tv1[j] = 3.0e38f; ti1[j] = 0x7fffffff;
    }
    #pragma unroll
    for (int c = 0; c < 8; ++c) {
        insert5(tv0, ti0, 1.0f - acc[0][c], col0w + c);
        insert5(tv1, ti1, 1.0f - acc[1][c], col0w + c);
    }

    // two-stage in-block merge across the 16 waves (8 LDS slots)
    __syncthreads();   // As dead; reuse LDS
    if (w < 8) {
        #pragma unroll
        for (int j = 0; j < K_SEL; ++j) {
            mval[(lane * 8 + w) * K_SEL + j] = tv0[j];
            midx[(lane * 8 + w) * K_SEL + j] = ti0[j];
            mval[((lane + 64) * 8 + w) * K_SEL + j] = tv1[j];
            midx[((lane + 64) * 8 + w) * K_SEL + j] = ti1[j];
        }
    }
    __syncthreads();
    if (w >= 8) {
        int s = w - 8;
        #pragma unroll
        for (int j = 0; j < K_SEL; ++j)
            insert5(tv0, ti0, mval[(lane * 8 + s) * K_SEL + j], midx[(lane * 8 + s) * K_SEL + j]);
        #pragma unroll
        for (int j = 0; j < K_SEL; ++j)
            insert5(tv1, ti1, mval[((lane + 64) * 8 + s) * K_SEL + j], midx[((lane + 64) * 8 + s) * K_SEL + j]);
        #pragma unroll
        for (int j = 0; j < K_SEL; ++j) {
            mval[(lane * 8 + s) * K_SEL + j] = tv0[j];
            midx[(lane * 8 + s) * K_SEL + j] = ti0[j];
            mval[((lane + 64) * 8 + s) * K_SEL + j] = tv1[j];
            midx[((lane + 64) * 8 + s) * K_SEL + j] = ti1[j];
        }
    }
    __syncthreads();
    if (tid < RTILE) {
        float fv[K_SEL]; int fi[K_SEL];
        #pragma unroll
        for (int j = 0; j < K_SEL; ++j) { fv[j] = 3.0e38f; fi[j] = 0x7fffffff; }
        for (int s = 0; s < 8; ++s)
            #pragma unroll
            for (int j = 0; j < K_SEL; ++j)
                insert5(fv, fi, mval[(tid * 8 + s) * K_SEL + j], midx[(tid * 8 + s) * K_SEL + j]);
        int grow = row0 + tid;
        #pragma unroll
        for (int j = 0; j < K_SEL; ++j) {
            cand_val[((size_t)grow * NCB + cb) * K_SEL + j] = fv[j];
            cand_idx[((size_t)grow * NCB + cb) * K_SEL + j] = fi[j];
        }
    }
}

__global__ __launch_bounds__(256)
void merge_kernel(const float* __restrict__ cand_val, const int* __restrict__ cand_idx,
                  float* __restrict__ out_dist, int* __restrict__ final_idx) {
    int row = blockIdx.x * blockDim.x + threadIdx.x;
    if (row >= B_ROWS) return;
    float fv[K_SEL]; int fi[K_SEL];
    #pragma unroll
    for (int j = 0; j < K_SEL; ++j) { fv[j] = 3.0e38f; fi[j] = 0x7fffffff; }
    for (int t = 0; t < NCB * K_SEL; ++t)
        insert5(fv, fi, cand_val[(size_t)row * NCB * K_SEL + t],
                        cand_idx[(size_t)row * NCB * K_SEL + t]);
    #pragma unroll
    for (int j = 0; j < K_SEL; ++j) {
        out_dist[(size_t)row * K_SEL + j] = fv[j];
        final_idx[(size_t)row * K_SEL + j] = fi[j];
    }
}

// one block per (b, s): copy prompts[idx] (5*768 floats = 960 float4) to output
__global__ __launch_bounds__(256)
void gather_kernel(const float* __restrict__ prompts, const int* __restrict__ final_idx,
                   float* __restrict__ out1) {
    int bs = blockIdx.x;                 // 0 .. B_ROWS*K_SEL-1
    int p = final_idx[bs];
    const float4* src = (const float4*)(prompts + (size_t)p * (L_LEN * D_DIM));
    float4* dst = (float4*)(out1 + (size_t)bs * (L_LEN * D_DIM));
    const int n4 = (L_LEN * D_DIM) / 4;  // 960
    for (int i = threadIdx.x; i < n4; i += blockDim.x) dst[i] = src[i];
}

extern "C" void kernel_launch(void* const* d_in, const int* in_sizes, int n_in,
                              void* d_out, int out_size, void* d_ws, size_t ws_size,
                              hipStream_t stream) {
    const float* x       = (const float*)d_in[0];   // [8192, 768]
    const float* pk      = (const float*)d_in[1];   // [2048, 768]
    const float* prompts = (const float*)d_in[2];   // [2048, 5, 768]

    float* out_dist = (float*)d_out;                          // [8192, 5]
    float* out_pr   = (float*)d_out + (size_t)B_ROWS * K_SEL; // [8192, 5, 5, 768]

    char* ws = (char*)d_ws;
    float* kn       = (float*)(ws);                              // 6,291,456 B
    float* inv_x    = (float*)(ws + 6291456);                    //    32,768 B
    float* cand_val = (float*)(ws + 6291456 + 32768);            // 2,621,440 B
    int*   cand_idx = (int*)  (ws + 6291456 + 32768 + 2621440);  // 2,621,440 B
    int*   final_ix = (int*)  (ws + 6291456 + 32768 + 2*2621440);//   163,840 B

    // 1) normalize keys -> kn; inverse norms for x
    norm_kernel<<<(P_KEYS + B_ROWS) / 4, 256, 0, stream>>>(x, pk, kn, inv_x);
    // 2) fused GEMM (SGPR-B from kn / LDS-A) + per-colblock top5
    {
        dim3 grid(NCB, B_ROWS / RTILE);
        gemm_top5_kernel<<<grid, 1024, 0, stream>>>(x, kn, inv_x, cand_val, cand_idx);
    }
    // 3) cross-colblock merge
    merge_kernel<<<B_ROWS / 256, 256, 0, stream>>>(cand_val, cand_idx, out_dist, final_ix);
    // 4) gather prompts
    gather_kernel<<<B_ROWS * K_SEL, 256, 0, stream>>>(prompts, final_ix, out_pr);
}